// Round 2
// baseline (387.913 us; speedup 1.0000x reference)
//
#include <hip/hip_runtime.h>
#include <hip/hip_bf16.h>
#include <cstdint>
#include <type_traits>

// SingleHeadAttention, split-bf16 precision plan:
//   scores need ~16 mantissa bits (row top-2 gaps can be < 10 vs score scale
//   ~8192; plain-bf16 noise sigma ~2-4 flips/shifts softmax on ~1% of rows ->
//   output errors up to ~90, matching round-1 absmax 93).
//   Q/K projections and QK^T run as 3-term split-bf16 MFMA (hh+hl+lh).
//   V / P / PV stay plain bf16 (output-side error ~0.3 << threshold 1.92).

using u16 = unsigned short;
typedef __attribute__((ext_vector_type(8))) short short8;
typedef __attribute__((ext_vector_type(4))) float floatx4;

static constexpr int S_SEQ = 4096;
static constexpr int D_IN  = 1024;
static constexpr int D_OUT = 1024;

// float -> bf16 bits, round-to-nearest-even
__device__ __forceinline__ u16 f2b(float f) {
  uint32_t u = __builtin_bit_cast(uint32_t, f);
  u = (u + 0x7FFFu + ((u >> 16) & 1u)) >> 16;
  return (u16)u;
}
__device__ __forceinline__ float b2f(u16 b) {
  return __builtin_bit_cast(float, (uint32_t)b << 16);
}

__device__ __forceinline__ void load16(const u16* g, u16* l) {
  // async global->LDS, 16B/lane; LDS dest must be wave-uniform base (+lane*16)
  __builtin_amdgcn_global_load_lds(
      (const __attribute__((address_space(1))) void*)g,
      (__attribute__((address_space(3))) void*)l,
      16, 0, 0);
}

// ---------------- conversion kernels ----------------

// X -> (hi, lo) bf16 pair
__global__ void split_bf16_kernel(const float* __restrict__ in,
                                  u16* __restrict__ hi, u16* __restrict__ lo,
                                  int n4) {
  int i = blockIdx.x * blockDim.x + threadIdx.x;
  if (i >= n4) return;
  float4 v = reinterpret_cast<const float4*>(in)[i];
  ushort4 h, l;
  h.x = f2b(v.x); l.x = f2b(v.x - b2f(h.x));
  h.y = f2b(v.y); l.y = f2b(v.y - b2f(h.y));
  h.z = f2b(v.z); l.z = f2b(v.z - b2f(h.z));
  h.w = f2b(v.w); l.w = f2b(v.w - b2f(h.w));
  reinterpret_cast<ushort4*>(hi)[i] = h;
  reinterpret_cast<ushort4*>(lo)[i] = l;
}

// outH/outL[c][r] = split(in[r][c]); n x n, n mult of 32. outL may be null.
__global__ void transpose_split_kernel(const float* __restrict__ in,
                                       u16* __restrict__ outH,
                                       u16* __restrict__ outL, int n) {
  __shared__ float tile[32][33];
  int bx = blockIdx.x * 32, by = blockIdx.y * 32;
  int tx = threadIdx.x, ty = threadIdx.y;   // block (32,8)
  for (int j = 0; j < 32; j += 8)
    tile[ty + j][tx] = in[(size_t)(by + ty + j) * n + bx + tx];
  __syncthreads();
  for (int j = 0; j < 32; j += 8) {
    float v = tile[tx][ty + j];
    u16 h = f2b(v);
    size_t idx = (size_t)(bx + ty + j) * n + by + tx;
    outH[idx] = h;
    if (outL) outL[idx] = f2b(v - b2f(h));
  }
}

// ---------------- GEMM ----------------
// C[m][n] = scale * sum_k A[m][k] * Bt[n][k]
// SPLIT_IN: A=(Ah+Al), Bt=(Bh+Bl); computes hh+hl+lh (ll dropped, ~2^-17 rel).
// OUTK: 0 = fp32 C (o0), 1 = bf16 C (o0),
//       2 = column-split + hi/lo split: cols [0,N/2) -> (o0=H,o1=L),
//           cols [N/2,N) -> (o2=H,o3=L), each with leading dim N/2.

template <bool SPLIT_IN, int OUTK>
__global__ __launch_bounds__(256)
void gemm_kernel(const u16* __restrict__ Ah, const u16* __restrict__ Al,
                 const u16* __restrict__ Bh, const u16* __restrict__ Bl,
                 void* __restrict__ o0, void* __restrict__ o1,
                 void* __restrict__ o2, void* __restrict__ o3,
                 int M, int N, int K, float scale) {
  constexpr int BM = 128, BN = 128, BK = 32;
  constexpr int TILE = BM * BK;                       // 4096 u16 = 8KB
  __shared__ __align__(16) u16 smem[SPLIT_IN ? 4 * TILE : 2 * TILE];
  u16* AsH = smem;
  u16* BsH = smem + TILE;
  u16* AsL = SPLIT_IN ? smem + 2 * TILE : nullptr;
  u16* BsL = SPLIT_IN ? smem + 3 * TILE : nullptr;

  const int tid  = threadIdx.x;
  const int wave = tid >> 6;
  const int lane = tid & 63;
  const int bm   = blockIdx.y * BM;
  const int bn   = blockIdx.x * BN;
  const int wm   = (wave >> 1) * 64;
  const int wn   = (wave & 1) * 64;
  const int quad = lane >> 4;
  const int l16  = lane & 15;

  // staging map: wave w covers rows [16w,16w+16) (and +64), 4 lanes/row
  const int srow = wave * 16 + (lane >> 2);
  const int scol = (lane & 3) * 8;
  const size_t offA = (size_t)(bm + srow) * K + scol;
  const size_t offB = (size_t)(bn + srow) * K + scol;
  const size_t off64 = (size_t)64 * K;
  const int lds0 = wave * 512;          // u16 offset of this wave's 1KB chunk
  const int lds1 = 2048 + wave * 512;

  floatx4 acc[4][4] = {};

  for (int k0 = 0; k0 < K; k0 += BK) {
    __syncthreads();                    // waves done reading previous tile
    load16(Ah + offA + k0,         AsH + lds0);
    load16(Ah + offA + off64 + k0, AsH + lds1);
    load16(Bh + offB + k0,         BsH + lds0);
    load16(Bh + offB + off64 + k0, BsH + lds1);
    if constexpr (SPLIT_IN) {
      load16(Al + offA + k0,         AsL + lds0);
      load16(Al + offA + off64 + k0, AsL + lds1);
      load16(Bl + offB + k0,         BsL + lds0);
      load16(Bl + offB + off64 + k0, BsL + lds1);
    }
    __syncthreads();                    // compiler drains vmcnt(0) first

    short8 ah[4], bh[4], al[4], bl[4];
#pragma unroll
    for (int t = 0; t < 4; ++t) {
      ah[t] = *reinterpret_cast<const short8*>(AsH + (wm + t * 16 + l16) * BK + quad * 8);
      bh[t] = *reinterpret_cast<const short8*>(BsH + (wn + t * 16 + l16) * BK + quad * 8);
      if constexpr (SPLIT_IN) {
        al[t] = *reinterpret_cast<const short8*>(AsL + (wm + t * 16 + l16) * BK + quad * 8);
        bl[t] = *reinterpret_cast<const short8*>(BsL + (wn + t * 16 + l16) * BK + quad * 8);
      }
    }

#pragma unroll
    for (int mt = 0; mt < 4; ++mt)
#pragma unroll
      for (int nt = 0; nt < 4; ++nt) {
        acc[mt][nt] = __builtin_amdgcn_mfma_f32_16x16x32_bf16(
            ah[mt], bh[nt], acc[mt][nt], 0, 0, 0);
        if constexpr (SPLIT_IN) {
          acc[mt][nt] = __builtin_amdgcn_mfma_f32_16x16x32_bf16(
              ah[mt], bl[nt], acc[mt][nt], 0, 0, 0);
          acc[mt][nt] = __builtin_amdgcn_mfma_f32_16x16x32_bf16(
              al[mt], bh[nt], acc[mt][nt], 0, 0, 0);
        }
      }
  }

  // epilogue: C/D layout col=lane&15, row=(lane>>4)*4+reg  [m89/m91]
  const int ncol0 = N >> 1;
#pragma unroll
  for (int mt = 0; mt < 4; ++mt) {
#pragma unroll
    for (int nt = 0; nt < 4; ++nt) {
      const int row = bm + wm + mt * 16 + quad * 4;
      const int col = bn + wn + nt * 16 + l16;
#pragma unroll
      for (int r = 0; r < 4; ++r) {
        float v = acc[mt][nt][r] * scale;
        if constexpr (OUTK == 0) {
          ((float*)o0)[(size_t)(row + r) * N + col] = v;
        } else if constexpr (OUTK == 1) {
          ((u16*)o0)[(size_t)(row + r) * N + col] = f2b(v);
        } else {
          const bool second = col >= ncol0;          // block-uniform (128|1024)
          u16* H = (u16*)(second ? o2 : o0);
          u16* L = (u16*)(second ? o3 : o1);
          const int c = second ? col - ncol0 : col;
          const size_t idx = (size_t)(row + r) * ncol0 + c;
          u16 h = f2b(v);
          H[idx] = h;
          L[idx] = f2b(v - b2f(h));
        }
      }
    }
  }
}

// ---------------- softmax ----------------

__global__ void row_stats_kernel(const float* __restrict__ S,
                                 float* __restrict__ mrow,
                                 float* __restrict__ linv) {
  const int row = blockIdx.x;
  const float* s = S + (size_t)row * S_SEQ;
  const int tid = threadIdx.x, lane = tid & 63, wave = tid >> 6;

  float m = -INFINITY, l = 0.f;
  for (int j = tid; j < S_SEQ; j += 256) {
    float x = s[j];
    float M = fmaxf(m, x);
    l = l * __expf(m - M) + __expf(x - M);
    m = M;
  }
#pragma unroll
  for (int off = 1; off < 64; off <<= 1) {
    float mo = __shfl_xor(m, off);
    float lo = __shfl_xor(l, off);
    float M = fmaxf(m, mo);
    l = l * __expf(m - M) + lo * __expf(mo - M);
    m = M;
  }
  __shared__ float sm[4], sl[4];
  if (lane == 0) { sm[wave] = m; sl[wave] = l; }
  __syncthreads();
  if (tid == 0) {
    m = sm[0]; l = sl[0];
    for (int w = 1; w < 4; ++w) {
      float M = fmaxf(m, sm[w]);
      l = l * __expf(m - M) + sl[w] * __expf(sm[w] - M);
      m = M;
    }
    mrow[row] = m;
    linv[row] = 1.f / l;
  }
}

__global__ void compute_p_kernel(const float* __restrict__ S,
                                 const float* __restrict__ mrow,
                                 const float* __restrict__ linv,
                                 u16* __restrict__ P) {
  const int row = blockIdx.y;
  const int c = (blockIdx.x * blockDim.x + threadIdx.x) * 4;
  const float m = mrow[row], li = linv[row];
  float4 s = *reinterpret_cast<const float4*>(S + (size_t)row * S_SEQ + c);
  ushort4 o;
  o.x = f2b(__expf(s.x - m) * li);
  o.y = f2b(__expf(s.y - m) * li);
  o.z = f2b(__expf(s.z - m) * li);
  o.w = f2b(__expf(s.w - m) * li);
  *reinterpret_cast<ushort4*>(P + (size_t)row * S_SEQ + c) = o;
}

// ---------------- launcher ----------------
// ws layout (~136.1 MB):
//  [0,8M)   Xh          [8M,16M)  Xl
//  [16M,20M) WqktH [2048][1024]   [20M,24M) WqktL
//  [24M,26M) Wvt  [1024][1024]
//  [0,32M)  P (overlays the above after projections)
//  [32M..]  Qh(8M) Ql(8M) Kh(8M) Kl(8M) Vt(8M)  -> [32M,72M)
//  [72M,136M)  S fp32 [4096][4096]
//  [136M..] mrow(16K) linv(16K)

extern "C" void kernel_launch(void* const* d_in, const int* in_sizes, int n_in,
                              void* d_out, int out_size, void* d_ws, size_t ws_size,
                              hipStream_t stream) {
  const float* X  = (const float*)d_in[0];
  const float* Wq = (const float*)d_in[1];
  const float* Wk = (const float*)d_in[2];
  const float* Wv = (const float*)d_in[3];
  float* O = (float*)d_out;
  char* ws = (char*)d_ws;

  const size_t MB = 1u << 20;
  u16*   Xh    = (u16*)(ws);
  u16*   Xl    = (u16*)(ws + 8 * MB);
  u16*   WqktH = (u16*)(ws + 16 * MB);   // rows 0..1023: Wq^T, 1024..2047: Wk^T
  u16*   WqktL = (u16*)(ws + 20 * MB);
  u16*   Wvt   = (u16*)(ws + 24 * MB);
  u16*   P     = (u16*)(ws);
  u16*   Qh    = (u16*)(ws + 32 * MB);
  u16*   Ql    = (u16*)(ws + 40 * MB);
  u16*   Kh    = (u16*)(ws + 48 * MB);
  u16*   Kl    = (u16*)(ws + 56 * MB);
  u16*   Vt    = (u16*)(ws + 64 * MB);   // [1024][4096]
  float* Ss    = (float*)(ws + 72 * MB);
  float* mrow  = (float*)(ws + 136 * MB);
  float* linv  = (float*)(ws + 136 * MB + 16384);

  // phase A: conversions
  split_bf16_kernel<<<(S_SEQ * D_IN / 4 + 255) / 256, 256, 0, stream>>>(
      X, Xh, Xl, S_SEQ * D_IN / 4);
  dim3 tb(32, 8);
  transpose_split_kernel<<<dim3(32, 32), tb, 0, stream>>>(Wq, WqktH, WqktL, 1024);
  transpose_split_kernel<<<dim3(32, 32), tb, 0, stream>>>(
      Wk, WqktH + 1024 * 1024, WqktL + 1024 * 1024, 1024);
  transpose_split_kernel<<<dim3(32, 32), tb, 0, stream>>>(Wv, Wvt, nullptr, 1024);

  // phase B: fused Q|K projection, split-in split-out
  gemm_kernel<true, 2><<<dim3(2048 / 128, S_SEQ / 128), 256, 0, stream>>>(
      Xh, Xl, WqktH, WqktL, Qh, Ql, Kh, Kl, S_SEQ, 2048, D_IN, 1.0f);
  // V^T = Wv^T · X^T, plain bf16
  gemm_kernel<false, 1><<<dim3(S_SEQ / 128, D_OUT / 128), 256, 0, stream>>>(
      Wvt, nullptr, Xh, nullptr, Vt, nullptr, nullptr, nullptr,
      D_OUT, S_SEQ, D_IN, 1.0f);

  // phase B2: S = (Q·K^T)/32, split-in, fp32 out
  gemm_kernel<true, 0><<<dim3(S_SEQ / 128, S_SEQ / 128), 256, 0, stream>>>(
      Qh, Ql, Kh, Kl, Ss, nullptr, nullptr, nullptr,
      S_SEQ, S_SEQ, D_OUT, 0.03125f);

  // phase C: softmax
  row_stats_kernel<<<S_SEQ, 256, 0, stream>>>(Ss, mrow, linv);
  compute_p_kernel<<<dim3(S_SEQ / 1024, S_SEQ), 256, 0, stream>>>(Ss, mrow, linv, P);

  // phase D: O = P·V
  gemm_kernel<false, 0><<<dim3(D_OUT / 128, S_SEQ / 128), 256, 0, stream>>>(
      P, nullptr, Vt, nullptr, O, nullptr, nullptr, nullptr,
      S_SEQ, D_OUT, S_SEQ, 1.0f);
}

// Round 3
// 339.804 us; speedup vs baseline: 1.1416x; 1.1416x over previous
//
#include <hip/hip_runtime.h>
#include <hip/hip_bf16.h>
#include <cstdint>
#include <type_traits>

// SingleHeadAttention, split-bf16 precision plan (validated round 2, absmax 0.75):
//   Q/K projections and QK^T run as 3-term split-bf16 MFMA (hh+hl+lh).
//   V / P / PV plain bf16. S kept fp32.
// Round-3 structure: merged QKV projection (768 blocks), split-K2 PV
// (512 blocks; 256 was 1 block/CU = ~2.5x slow per m102), single-pass softmax.

using u16 = unsigned short;
typedef __attribute__((ext_vector_type(8))) short short8;
typedef __attribute__((ext_vector_type(4))) float floatx4;

static constexpr int S_SEQ = 4096;
static constexpr int D_IN  = 1024;
static constexpr int D_OUT = 1024;

__device__ __forceinline__ u16 f2b(float f) {
  uint32_t u = __builtin_bit_cast(uint32_t, f);
  u = (u + 0x7FFFu + ((u >> 16) & 1u)) >> 16;
  return (u16)u;
}
__device__ __forceinline__ float b2f(u16 b) {
  return __builtin_bit_cast(float, (uint32_t)b << 16);
}
__device__ __forceinline__ void load16(const u16* g, u16* l) {
  __builtin_amdgcn_global_load_lds(
      (const __attribute__((address_space(1))) void*)g,
      (__attribute__((address_space(3))) void*)l,
      16, 0, 0);
}

// ---------------- conversions ----------------

__global__ void split_bf16_kernel(const float* __restrict__ in,
                                  u16* __restrict__ hi, u16* __restrict__ lo,
                                  int n4) {
  int i = blockIdx.x * blockDim.x + threadIdx.x;
  if (i >= n4) return;
  float4 v = reinterpret_cast<const float4*>(in)[i];
  ushort4 h, l;
  h.x = f2b(v.x); l.x = f2b(v.x - b2f(h.x));
  h.y = f2b(v.y); l.y = f2b(v.y - b2f(h.y));
  h.z = f2b(v.z); l.z = f2b(v.z - b2f(h.z));
  h.w = f2b(v.w); l.w = f2b(v.w - b2f(h.w));
  reinterpret_cast<ushort4*>(hi)[i] = h;
  reinterpret_cast<ushort4*>(lo)[i] = l;
}

// z=0:Wq z=1:Wk (split H+L), z=2:Wv (H only). WtH[3072][1024], WtL[2048][1024]
__global__ void transpose_w_kernel(const float* __restrict__ Wq,
                                   const float* __restrict__ Wk,
                                   const float* __restrict__ Wv,
                                   u16* __restrict__ WtH, u16* __restrict__ WtL) {
  const int z = blockIdx.z;
  const float* src = (z == 0) ? Wq : (z == 1) ? Wk : Wv;
  u16* dH = WtH + (size_t)z * 1024 * 1024;
  u16* dL = (z < 2) ? WtL + (size_t)z * 1024 * 1024 : nullptr;
  __shared__ float tile[32][33];
  int bx = blockIdx.x * 32, by = blockIdx.y * 32;
  int tx = threadIdx.x, ty = threadIdx.y;   // block (32,8)
  for (int j = 0; j < 32; j += 8)
    tile[ty + j][tx] = src[(size_t)(by + ty + j) * 1024 + bx + tx];
  __syncthreads();
  for (int j = 0; j < 32; j += 8) {
    float v = tile[tx][ty + j];
    u16 h = f2b(v);
    size_t idx = (size_t)(bx + ty + j) * 1024 + by + tx;
    dH[idx] = h;
    if (dL) dL[idx] = f2b(v - b2f(h));
  }
}

// ---------------- merged QKV projection ----------------
// A = X (split), B rows: [0,1024)=Wq^T(H,L) [1024,2048)=Wk^T(H,L) [2048,3072)=Wv^T(H)
// Out: Q -> Qh/Ql split, K -> Kh/Kl split, V -> Vt[1024][4096] bf16 (transposed).
__global__ __launch_bounds__(256)
void qkv_kernel(const u16* __restrict__ Xh, const u16* __restrict__ Xl,
                const u16* __restrict__ WtH, const u16* __restrict__ WtL,
                u16* __restrict__ Qh, u16* __restrict__ Ql,
                u16* __restrict__ Kh, u16* __restrict__ Kl,
                u16* __restrict__ Vt) {
  constexpr int BK = 32, K = D_IN;
  constexpr int TILE = 128 * BK;
  __shared__ __align__(16) u16 smem[4 * TILE];
  u16* AsH = smem;
  u16* BsH = smem + TILE;
  u16* AsL = smem + 2 * TILE;
  u16* BsL = smem + 3 * TILE;

  const int tid  = threadIdx.x;
  const int wave = tid >> 6;
  const int lane = tid & 63;
  const int bm   = blockIdx.y * 128;
  const int bn   = blockIdx.x * 128;     // in [0,3072)
  const bool splitB = bn < 2048;         // Q/K blocks need 3-term
  const int wm   = (wave >> 1) * 64;
  const int wn   = (wave & 1) * 64;
  const int quad = lane >> 4;
  const int l16  = lane & 15;

  const int srow = wave * 16 + (lane >> 2);
  const int scol = (lane & 3) * 8;
  const size_t offA = (size_t)(bm + srow) * K + scol;
  const size_t offB = (size_t)(bn + srow) * K + scol;
  const size_t off64 = (size_t)64 * K;
  const int lds0 = wave * 512;
  const int lds1 = 2048 + wave * 512;

  floatx4 acc[4][4] = {};

  for (int k0 = 0; k0 < K; k0 += BK) {
    __syncthreads();
    load16(Xh + offA + k0,          AsH + lds0);
    load16(Xh + offA + off64 + k0,  AsH + lds1);
    load16(WtH + offB + k0,         BsH + lds0);
    load16(WtH + offB + off64 + k0, BsH + lds1);
    if (splitB) {
      load16(Xl + offA + k0,          AsL + lds0);
      load16(Xl + offA + off64 + k0,  AsL + lds1);
      load16(WtL + offB + k0,         BsL + lds0);
      load16(WtL + offB + off64 + k0, BsL + lds1);
    }
    __syncthreads();

    short8 ah[4], bh[4], al[4], bl[4];
#pragma unroll
    for (int t = 0; t < 4; ++t) {
      ah[t] = *reinterpret_cast<const short8*>(AsH + (wm + t * 16 + l16) * BK + quad * 8);
      bh[t] = *reinterpret_cast<const short8*>(BsH + (wn + t * 16 + l16) * BK + quad * 8);
    }
    if (splitB) {
#pragma unroll
      for (int t = 0; t < 4; ++t) {
        al[t] = *reinterpret_cast<const short8*>(AsL + (wm + t * 16 + l16) * BK + quad * 8);
        bl[t] = *reinterpret_cast<const short8*>(BsL + (wn + t * 16 + l16) * BK + quad * 8);
      }
    }

#pragma unroll
    for (int mt = 0; mt < 4; ++mt)
#pragma unroll
      for (int nt = 0; nt < 4; ++nt)
        acc[mt][nt] = __builtin_amdgcn_mfma_f32_16x16x32_bf16(
            ah[mt], bh[nt], acc[mt][nt], 0, 0, 0);
    if (splitB) {
#pragma unroll
      for (int mt = 0; mt < 4; ++mt)
#pragma unroll
        for (int nt = 0; nt < 4; ++nt) {
          acc[mt][nt] = __builtin_amdgcn_mfma_f32_16x16x32_bf16(
              ah[mt], bl[nt], acc[mt][nt], 0, 0, 0);
          acc[mt][nt] = __builtin_amdgcn_mfma_f32_16x16x32_bf16(
              al[mt], bh[nt], acc[mt][nt], 0, 0, 0);
        }
    }
  }

  // epilogue (C/D: col=lane&15, row=quad*4+reg)
#pragma unroll
  for (int mt = 0; mt < 4; ++mt) {
#pragma unroll
    for (int nt = 0; nt < 4; ++nt) {
      const int row = bm + wm + mt * 16 + quad * 4;
      const int col = bn + wn + nt * 16 + l16;
      if (bn < 1024) {                 // Q, split out
#pragma unroll
        for (int r = 0; r < 4; ++r) {
          float v = acc[mt][nt][r];
          u16 h = f2b(v);
          size_t idx = (size_t)(row + r) * D_OUT + col;
          Qh[idx] = h; Ql[idx] = f2b(v - b2f(h));
        }
      } else if (bn < 2048) {          // K, split out
#pragma unroll
        for (int r = 0; r < 4; ++r) {
          float v = acc[mt][nt][r];
          u16 h = f2b(v);
          size_t idx = (size_t)(row + r) * D_OUT + (col - 1024);
          Kh[idx] = h; Kl[idx] = f2b(v - b2f(h));
        }
      } else {                         // V, write transposed, packed 8B store
        ushort4 o;
        o.x = f2b(acc[mt][nt][0]);
        o.y = f2b(acc[mt][nt][1]);
        o.z = f2b(acc[mt][nt][2]);
        o.w = f2b(acc[mt][nt][3]);
        *reinterpret_cast<ushort4*>(Vt + (size_t)(col - 2048) * S_SEQ + row) = o;
      }
    }
  }
}

// ---------------- generic GEMM (fp32 out) ----------------
// C[z][m][n] = scale * sum_{k<K} A[m][z*K+k] * Bt[n][z*K+k]   (z = blockIdx.z)
template <bool SPLIT_IN>
__global__ __launch_bounds__(256)
void gemm_kernel(const u16* __restrict__ Ah, const u16* __restrict__ Al,
                 const u16* __restrict__ Bh, const u16* __restrict__ Bl,
                 float* __restrict__ C, int M, int N, int K,
                 int lda, int ldb, float scale) {
  constexpr int BK = 32;
  constexpr int TILE = 128 * BK;
  __shared__ __align__(16) u16 smem[(SPLIT_IN ? 4 : 2) * TILE];
  u16* AsH = smem;
  u16* BsH = smem + TILE;
  u16* AsL = SPLIT_IN ? smem + 2 * TILE : nullptr;
  u16* BsL = SPLIT_IN ? smem + 3 * TILE : nullptr;

  const size_t kof = (size_t)blockIdx.z * K;
  Ah += kof; Bh += kof;
  if (SPLIT_IN) { Al += kof; Bl += kof; }
  C += (size_t)blockIdx.z * M * N;

  const int tid  = threadIdx.x;
  const int wave = tid >> 6;
  const int lane = tid & 63;
  const int bm   = blockIdx.y * 128;
  const int bn   = blockIdx.x * 128;
  const int wm   = (wave >> 1) * 64;
  const int wn   = (wave & 1) * 64;
  const int quad = lane >> 4;
  const int l16  = lane & 15;

  const int srow = wave * 16 + (lane >> 2);
  const int scol = (lane & 3) * 8;
  const size_t offA = (size_t)(bm + srow) * lda + scol;
  const size_t offB = (size_t)(bn + srow) * ldb + scol;
  const size_t offA64 = (size_t)64 * lda;
  const size_t offB64 = (size_t)64 * ldb;
  const int lds0 = wave * 512;
  const int lds1 = 2048 + wave * 512;

  floatx4 acc[4][4] = {};

  for (int k0 = 0; k0 < K; k0 += BK) {
    __syncthreads();
    load16(Ah + offA + k0,          AsH + lds0);
    load16(Ah + offA + offA64 + k0, AsH + lds1);
    load16(Bh + offB + k0,          BsH + lds0);
    load16(Bh + offB + offB64 + k0, BsH + lds1);
    if constexpr (SPLIT_IN) {
      load16(Al + offA + k0,          AsL + lds0);
      load16(Al + offA + offA64 + k0, AsL + lds1);
      load16(Bl + offB + k0,          BsL + lds0);
      load16(Bl + offB + offB64 + k0, BsL + lds1);
    }
    __syncthreads();

    short8 ah[4], bh[4], al[4], bl[4];
#pragma unroll
    for (int t = 0; t < 4; ++t) {
      ah[t] = *reinterpret_cast<const short8*>(AsH + (wm + t * 16 + l16) * BK + quad * 8);
      bh[t] = *reinterpret_cast<const short8*>(BsH + (wn + t * 16 + l16) * BK + quad * 8);
      if constexpr (SPLIT_IN) {
        al[t] = *reinterpret_cast<const short8*>(AsL + (wm + t * 16 + l16) * BK + quad * 8);
        bl[t] = *reinterpret_cast<const short8*>(BsL + (wn + t * 16 + l16) * BK + quad * 8);
      }
    }

#pragma unroll
    for (int mt = 0; mt < 4; ++mt)
#pragma unroll
      for (int nt = 0; nt < 4; ++nt) {
        acc[mt][nt] = __builtin_amdgcn_mfma_f32_16x16x32_bf16(
            ah[mt], bh[nt], acc[mt][nt], 0, 0, 0);
        if constexpr (SPLIT_IN) {
          acc[mt][nt] = __builtin_amdgcn_mfma_f32_16x16x32_bf16(
              ah[mt], bl[nt], acc[mt][nt], 0, 0, 0);
          acc[mt][nt] = __builtin_amdgcn_mfma_f32_16x16x32_bf16(
              al[mt], bh[nt], acc[mt][nt], 0, 0, 0);
        }
      }
  }

#pragma unroll
  for (int mt = 0; mt < 4; ++mt)
#pragma unroll
    for (int nt = 0; nt < 4; ++nt) {
      const int row = bm + wm + mt * 16 + quad * 4;
      const int col = bn + wn + nt * 16 + l16;
#pragma unroll
      for (int r = 0; r < 4; ++r)
        C[(size_t)(row + r) * N + col] = acc[mt][nt][r] * scale;
    }
}

// ---------------- single-pass softmax (block per row) ----------------
__global__ __launch_bounds__(256)
void softmax_kernel(const float* __restrict__ S, u16* __restrict__ P) {
  const int row = blockIdx.x, tid = threadIdx.x;
  const int lane = tid & 63, wave = tid >> 6;
  __shared__ float red[4];
  const float4* src = reinterpret_cast<const float4*>(S + (size_t)row * S_SEQ);
  ushort4* dst = reinterpret_cast<ushort4*>(P + (size_t)row * S_SEQ);

  float4 v[4];
  float m = -INFINITY;
#pragma unroll
  for (int t = 0; t < 4; ++t) {
    v[t] = src[tid + t * 256];
    m = fmaxf(m, fmaxf(fmaxf(v[t].x, v[t].y), fmaxf(v[t].z, v[t].w)));
  }
#pragma unroll
  for (int off = 1; off < 64; off <<= 1) m = fmaxf(m, __shfl_xor(m, off));
  if (lane == 0) red[wave] = m;
  __syncthreads();
  m = fmaxf(fmaxf(red[0], red[1]), fmaxf(red[2], red[3]));

  float e[16];
  float l = 0.f;
#pragma unroll
  for (int t = 0; t < 4; ++t) {
    e[4 * t + 0] = __expf(v[t].x - m);
    e[4 * t + 1] = __expf(v[t].y - m);
    e[4 * t + 2] = __expf(v[t].z - m);
    e[4 * t + 3] = __expf(v[t].w - m);
    l += e[4 * t + 0] + e[4 * t + 1] + e[4 * t + 2] + e[4 * t + 3];
  }
#pragma unroll
  for (int off = 1; off < 64; off <<= 1) l += __shfl_xor(l, off);
  __syncthreads();                       // red reuse
  if (lane == 0) red[wave] = l;
  __syncthreads();
  const float li = 1.f / (red[0] + red[1] + red[2] + red[3]);

#pragma unroll
  for (int t = 0; t < 4; ++t) {
    ushort4 o;
    o.x = f2b(e[4 * t + 0] * li);
    o.y = f2b(e[4 * t + 1] * li);
    o.z = f2b(e[4 * t + 2] * li);
    o.w = f2b(e[4 * t + 3] * li);
    dst[tid + t * 256] = o;
  }
}

// ---------------- split-K reduce ----------------
__global__ void add_kernel(const float* __restrict__ a, const float* __restrict__ b,
                           float* __restrict__ o, int n4) {
  int i = blockIdx.x * blockDim.x + threadIdx.x;
  if (i >= n4) return;
  float4 x = reinterpret_cast<const float4*>(a)[i];
  float4 y = reinterpret_cast<const float4*>(b)[i];
  x.x += y.x; x.y += y.y; x.z += y.z; x.w += y.w;
  reinterpret_cast<float4*>(o)[i] = x;
}

// ---------------- launcher ----------------
// ws (136 MB):
//  [0,8M) Xh   [8,16M) Xl   [16,22M) WtH[3072][1024]  [22,26M) WtL[2048][1024]
//  [0,32M)  P (overlays X/W after projections)
//  [32,40) Qh  [40,48) Ql  [48,56) Kh  [56,64) Kl  [64,72) Vt[1024][4096]
//  [32,48) O0 / [48,64) O1 (overlay Q/K after S GEMM)
//  [72,136) Ss fp32 [4096][4096]

extern "C" void kernel_launch(void* const* d_in, const int* in_sizes, int n_in,
                              void* d_out, int out_size, void* d_ws, size_t ws_size,
                              hipStream_t stream) {
  const float* X  = (const float*)d_in[0];
  const float* Wq = (const float*)d_in[1];
  const float* Wk = (const float*)d_in[2];
  const float* Wv = (const float*)d_in[3];
  float* O = (float*)d_out;
  char* ws = (char*)d_ws;

  const size_t MB = 1u << 20;
  u16*   Xh  = (u16*)(ws);
  u16*   Xl  = (u16*)(ws + 8 * MB);
  u16*   WtH = (u16*)(ws + 16 * MB);
  u16*   WtL = (u16*)(ws + 22 * MB);
  u16*   P   = (u16*)(ws);
  u16*   Qh  = (u16*)(ws + 32 * MB);
  u16*   Ql  = (u16*)(ws + 40 * MB);
  u16*   Kh  = (u16*)(ws + 48 * MB);
  u16*   Kl  = (u16*)(ws + 56 * MB);
  u16*   Vt  = (u16*)(ws + 64 * MB);
  float* O0  = (float*)(ws + 32 * MB);   // overlays Qh/Ql (dead after S GEMM)
  float* O1  = (float*)(ws + 48 * MB);   // overlays Kh/Kl
  float* Ss  = (float*)(ws + 72 * MB);

  // phase A: conversions (2 launches)
  split_bf16_kernel<<<(S_SEQ * D_IN / 4 + 255) / 256, 256, 0, stream>>>(
      X, Xh, Xl, S_SEQ * D_IN / 4);
  transpose_w_kernel<<<dim3(32, 32, 3), dim3(32, 8), 0, stream>>>(
      Wq, Wk, Wv, WtH, WtL);

  // phase B: merged QKV projection, 768 blocks (3 blocks/CU)
  qkv_kernel<<<dim3(3072 / 128, S_SEQ / 128), 256, 0, stream>>>(
      Xh, Xl, WtH, WtL, Qh, Ql, Kh, Kl, Vt);

  // phase B2: S = (Q.K^T)/32, split-in, fp32
  gemm_kernel<true><<<dim3(S_SEQ / 128, S_SEQ / 128), 256, 0, stream>>>(
      Qh, Ql, Kh, Kl, Ss, S_SEQ, S_SEQ, D_OUT, D_OUT, D_OUT, 0.03125f);

  // phase C: single-pass softmax
  softmax_kernel<<<S_SEQ, 256, 0, stream>>>(Ss, P);

  // phase D: O = P.V, split-K2 (512 blocks), then reduce
  gemm_kernel<false><<<dim3(D_OUT / 128, S_SEQ / 128, 2), 256, 0, stream>>>(
      P, nullptr, Vt, nullptr, O0, S_SEQ, D_OUT, S_SEQ / 2, S_SEQ, S_SEQ, 1.0f);
  add_kernel<<<(S_SEQ * D_OUT / 4 + 255) / 256, 256, 0, stream>>>(
      O0, O1, O, S_SEQ * D_OUT / 4);
}

// Round 4
// 318.686 us; speedup vs baseline: 1.2172x; 1.0663x over previous
//
#include <hip/hip_runtime.h>
#include <hip/hip_bf16.h>
#include <cstdint>
#include <type_traits>

// SingleHeadAttention. Precision plan (validated r2/r3, absmax 0.75):
//   scores need ~16 mantissa bits. r3 did it with 3-term split-bf16 (3x MFMA).
//   r4: S GEMM in int8 FIXED-POINT: q16=rint(Q*256) split into hi/lo bytes;
//   S = AC<<16 + (AD+BC)<<8 + BD, exact int32 accumulation, 4 i8-MFMA classes
//   at 2x OPS/inst => ~0.67x MFMA-busy vs 3-term bf16. Repr noise sigma~0.03
//   on scores (same class as before). QKV proj stays 3-term split-bf16;
//   V/P/PV plain bf16. PV split-K2 accumulates into O via fp32 atomicAdd
//   after hipMemsetAsync(O,0) (replaces add_kernel).

using u16 = unsigned short;
typedef __attribute__((ext_vector_type(8))) short short8;
typedef __attribute__((ext_vector_type(4))) float floatx4;
typedef __attribute__((ext_vector_type(4))) int intx4;

static constexpr int S_SEQ = 4096;
static constexpr int D_IN  = 1024;
static constexpr int D_OUT = 1024;

__device__ __forceinline__ u16 f2b(float f) {
  uint32_t u = __builtin_bit_cast(uint32_t, f);
  u = (u + 0x7FFFu + ((u >> 16) & 1u)) >> 16;
  return (u16)u;
}
__device__ __forceinline__ float b2f(u16 b) {
  return __builtin_bit_cast(float, (uint32_t)b << 16);
}
__device__ __forceinline__ void load16(const void* g, void* l) {
  __builtin_amdgcn_global_load_lds(
      (const __attribute__((address_space(1))) void*)g,
      (__attribute__((address_space(3))) void*)l,
      16, 0, 0);
}

// ---------------- conversions ----------------

__global__ void split_bf16_kernel(const float* __restrict__ in,
                                  u16* __restrict__ hi, u16* __restrict__ lo,
                                  int n4) {
  int i = blockIdx.x * blockDim.x + threadIdx.x;
  if (i >= n4) return;
  float4 v = reinterpret_cast<const float4*>(in)[i];
  ushort4 h, l;
  h.x = f2b(v.x); l.x = f2b(v.x - b2f(h.x));
  h.y = f2b(v.y); l.y = f2b(v.y - b2f(h.y));
  h.z = f2b(v.z); l.z = f2b(v.z - b2f(h.z));
  h.w = f2b(v.w); l.w = f2b(v.w - b2f(h.w));
  reinterpret_cast<ushort4*>(hi)[i] = h;
  reinterpret_cast<ushort4*>(lo)[i] = l;
}

// z=0:Wq z=1:Wk (split H+L), z=2:Wv (H only). WtH[3072][1024], WtL[2048][1024]
__global__ void transpose_w_kernel(const float* __restrict__ Wq,
                                   const float* __restrict__ Wk,
                                   const float* __restrict__ Wv,
                                   u16* __restrict__ WtH, u16* __restrict__ WtL) {
  const int z = blockIdx.z;
  const float* src = (z == 0) ? Wq : (z == 1) ? Wk : Wv;
  u16* dH = WtH + (size_t)z * 1024 * 1024;
  u16* dL = (z < 2) ? WtL + (size_t)z * 1024 * 1024 : nullptr;
  __shared__ float tile[32][33];
  int bx = blockIdx.x * 32, by = blockIdx.y * 32;
  int tx = threadIdx.x, ty = threadIdx.y;   // block (32,8)
  for (int j = 0; j < 32; j += 8)
    tile[ty + j][tx] = src[(size_t)(by + ty + j) * 1024 + bx + tx];
  __syncthreads();
  for (int j = 0; j < 32; j += 8) {
    float v = tile[tx][ty + j];
    u16 h = f2b(v);
    size_t idx = (size_t)(bx + ty + j) * 1024 + by + tx;
    dH[idx] = h;
    if (dL) dL[idx] = f2b(v - b2f(h));
  }
}

// ---------------- merged QKV projection (split-bf16 compute) ----------------
// Out: Q,K -> int16-fixed hi/lo byte planes (scale 2^-8); V -> Vt bf16 transposed.
__global__ __launch_bounds__(256)
void qkv_kernel(const u16* __restrict__ Xh, const u16* __restrict__ Xl,
                const u16* __restrict__ WtH, const u16* __restrict__ WtL,
                char* __restrict__ Qa, char* __restrict__ Qb,
                char* __restrict__ Ka, char* __restrict__ Kb,
                u16* __restrict__ Vt) {
  constexpr int BK = 32, K = D_IN;
  constexpr int TILE = 128 * BK;
  __shared__ __align__(16) u16 smem[4 * TILE];
  u16* AsH = smem;
  u16* BsH = smem + TILE;
  u16* AsL = smem + 2 * TILE;
  u16* BsL = smem + 3 * TILE;

  const int tid  = threadIdx.x;
  const int wave = tid >> 6;
  const int lane = tid & 63;
  const int bm   = blockIdx.y * 128;
  const int bn   = blockIdx.x * 128;     // [0,3072)
  const bool splitB = bn < 2048;
  const int wm   = (wave >> 1) * 64;
  const int wn   = (wave & 1) * 64;
  const int quad = lane >> 4;
  const int l16  = lane & 15;

  const int srow = wave * 16 + (lane >> 2);
  const int scol = (lane & 3) * 8;
  const size_t offA = (size_t)(bm + srow) * K + scol;
  const size_t offB = (size_t)(bn + srow) * K + scol;
  const size_t off64 = (size_t)64 * K;
  const int lds0 = wave * 512;
  const int lds1 = 2048 + wave * 512;

  floatx4 acc[4][4] = {};

  for (int k0 = 0; k0 < K; k0 += BK) {
    __syncthreads();
    load16(Xh + offA + k0,          AsH + lds0);
    load16(Xh + offA + off64 + k0,  AsH + lds1);
    load16(WtH + offB + k0,         BsH + lds0);
    load16(WtH + offB + off64 + k0, BsH + lds1);
    if (splitB) {
      load16(Xl + offA + k0,          AsL + lds0);
      load16(Xl + offA + off64 + k0,  AsL + lds1);
      load16(WtL + offB + k0,         BsL + lds0);
      load16(WtL + offB + off64 + k0, BsL + lds1);
    }
    __syncthreads();

    short8 ah[4], bh[4], al[4], bl[4];
#pragma unroll
    for (int t = 0; t < 4; ++t) {
      ah[t] = *reinterpret_cast<const short8*>(AsH + (wm + t * 16 + l16) * BK + quad * 8);
      bh[t] = *reinterpret_cast<const short8*>(BsH + (wn + t * 16 + l16) * BK + quad * 8);
    }
    if (splitB) {
#pragma unroll
      for (int t = 0; t < 4; ++t) {
        al[t] = *reinterpret_cast<const short8*>(AsL + (wm + t * 16 + l16) * BK + quad * 8);
        bl[t] = *reinterpret_cast<const short8*>(BsL + (wn + t * 16 + l16) * BK + quad * 8);
      }
    }

#pragma unroll
    for (int mt = 0; mt < 4; ++mt)
#pragma unroll
      for (int nt = 0; nt < 4; ++nt)
        acc[mt][nt] = __builtin_amdgcn_mfma_f32_16x16x32_bf16(
            ah[mt], bh[nt], acc[mt][nt], 0, 0, 0);
    if (splitB) {
#pragma unroll
      for (int mt = 0; mt < 4; ++mt)
#pragma unroll
        for (int nt = 0; nt < 4; ++nt) {
          acc[mt][nt] = __builtin_amdgcn_mfma_f32_16x16x32_bf16(
              ah[mt], bl[nt], acc[mt][nt], 0, 0, 0);
          acc[mt][nt] = __builtin_amdgcn_mfma_f32_16x16x32_bf16(
              al[mt], bh[nt], acc[mt][nt], 0, 0, 0);
        }
    }
  }

  // epilogue (C/D: col=lane&15, row=quad*4+reg)
#pragma unroll
  for (int mt = 0; mt < 4; ++mt) {
#pragma unroll
    for (int nt = 0; nt < 4; ++nt) {
      const int row = bm + wm + mt * 16 + quad * 4;
      const int col = bn + wn + nt * 16 + l16;
      if (bn < 2048) {                 // Q or K -> int16-fixed byte planes
        char* Pa = (bn < 1024) ? Qa : Ka;
        char* Pb = (bn < 1024) ? Qb : Kb;
        const int c = (bn < 1024) ? col : col - 1024;
#pragma unroll
        for (int r = 0; r < 4; ++r) {
          float v = acc[mt][nt][r];
          int q16 = (int)rintf(v * 256.f);
          q16 = min(max(q16, -32512), 32512);    // |Q| <= 127 (6.9 sigma)
          int a = (q16 + 128) >> 8;              // a in [-127,127]
          int b = q16 - (a << 8);                // b in [-128,127]
          size_t idx = (size_t)(row + r) * 1024 + c;
          Pa[idx] = (char)a;
          Pb[idx] = (char)b;
        }
      } else {                         // V, write transposed, packed 8B store
        ushort4 o;
        o.x = f2b(acc[mt][nt][0]);
        o.y = f2b(acc[mt][nt][1]);
        o.z = f2b(acc[mt][nt][2]);
        o.w = f2b(acc[mt][nt][3]);
        *reinterpret_cast<ushort4*>(Vt + (size_t)(col - 2048) * S_SEQ + row) = o;
      }
    }
  }
}

// ---------------- i8 fixed-point S GEMM ----------------
// S[m][n] = ((sum a_q a_k)<<16 + (sum a_q b_k + b_q a_k)<<8 + (sum b_q b_k)) * 2^-21
// Tile 128x64, BK=64, 4 waves (2x2) each 64x32. 3 int32 acc classes.
__global__ __launch_bounds__(256)
void s_i8_kernel(const char* __restrict__ Qa, const char* __restrict__ Qb,
                 const char* __restrict__ Ka, const char* __restrict__ Kb,
                 float* __restrict__ S) {
  constexpr int K = D_IN, BK = 64;
  __shared__ __align__(16) char smem[24 * 1024];
  char* QaS = smem;                // [128][64]
  char* QbS = smem + 8192;         // [128][64]
  char* KaS = smem + 16384;        // [64][64]
  char* KbS = smem + 20480;        // [64][64]

  const int tid  = threadIdx.x;
  const int wave = tid >> 6;
  const int lane = tid & 63;
  const int bm   = blockIdx.y * 128;
  const int bn   = blockIdx.x * 64;
  const int wm   = (wave >> 1) * 64;
  const int wn   = (wave & 1) * 32;
  const int quad = lane >> 4;
  const int l16  = lane & 15;

  // staging: 16-row x 64B chunks, 4 lanes/row, 16B/lane
  const int srow = (lane >> 2);
  const int scol = (lane & 3) * 16;
  const size_t gA0 = (size_t)(bm + wave * 16 + srow) * K + scol;       // chunk w
  const size_t gA1 = gA0 + (size_t)64 * K;                             // chunk w+4
  const size_t gB  = (size_t)(bn + wave * 16 + srow) * K + scol;       // chunk w
  const int lA0 = wave * 1024, lA1 = 4096 + wave * 1024, lB = wave * 1024;

  intx4 accH[4][2] = {};
  intx4 accM[4][2] = {};
  intx4 accL[4][2] = {};

  for (int k0 = 0; k0 < K; k0 += BK) {
    __syncthreads();
    load16(Qa + gA0 + k0, QaS + lA0);
    load16(Qa + gA1 + k0, QaS + lA1);
    load16(Qb + gA0 + k0, QbS + lA0);
    load16(Qb + gA1 + k0, QbS + lA1);
    load16(Ka + gB + k0,  KaS + lB);
    load16(Kb + gB + k0,  KbS + lB);
    __syncthreads();

    intx4 ah[4], al[4];
#pragma unroll
    for (int t = 0; t < 4; ++t) {
      ah[t] = *reinterpret_cast<const intx4*>(QaS + (wm + t * 16 + l16) * 64 + quad * 16);
      al[t] = *reinterpret_cast<const intx4*>(QbS + (wm + t * 16 + l16) * 64 + quad * 16);
    }
    // B-part-major: only one B fragment live at a time (register pressure)
#pragma unroll
    for (int nt = 0; nt < 2; ++nt) {
      intx4 bh = *reinterpret_cast<const intx4*>(KaS + (wn + nt * 16 + l16) * 64 + quad * 16);
#pragma unroll
      for (int mt = 0; mt < 4; ++mt) {
        accH[mt][nt] = __builtin_amdgcn_mfma_i32_16x16x64_i8(ah[mt], bh, accH[mt][nt], 0, 0, 0);
        accM[mt][nt] = __builtin_amdgcn_mfma_i32_16x16x64_i8(al[mt], bh, accM[mt][nt], 0, 0, 0);
      }
      intx4 bl = *reinterpret_cast<const intx4*>(KbS + (wn + nt * 16 + l16) * 64 + quad * 16);
#pragma unroll
      for (int mt = 0; mt < 4; ++mt) {
        accM[mt][nt] = __builtin_amdgcn_mfma_i32_16x16x64_i8(ah[mt], bl, accM[mt][nt], 0, 0, 0);
        accL[mt][nt] = __builtin_amdgcn_mfma_i32_16x16x64_i8(al[mt], bl, accL[mt][nt], 0, 0, 0);
      }
    }
  }

  // epilogue: exact int64 recombine, scale = 2^-16 (fixed) * 2^-5 (1/32) = 2^-21
  constexpr float SC = 4.76837158203125e-07f;
#pragma unroll
  for (int mt = 0; mt < 4; ++mt)
#pragma unroll
    for (int nt = 0; nt < 2; ++nt) {
      const int row = bm + wm + mt * 16 + quad * 4;
      const int col = bn + wn + nt * 16 + l16;
#pragma unroll
      for (int r = 0; r < 4; ++r) {
        long long fix = (((long long)accH[mt][nt][r]) << 16) +
                        (((long long)accM[mt][nt][r]) << 8) +
                        (long long)accL[mt][nt][r];
        S[(size_t)(row + r) * S_SEQ + col] = (float)fix * SC;
      }
    }
}

// ---------------- bf16 GEMM (PV) ----------------
// C[m][n] (+)= sum_k A[m][z*K+k] * Bt[n][z*K+k]
template <bool ATOMIC>
__global__ __launch_bounds__(256)
void gemm_kernel(const u16* __restrict__ A, const u16* __restrict__ Bt,
                 float* __restrict__ C, int M, int N, int K,
                 int lda, int ldb) {
  constexpr int BK = 32;
  constexpr int TILE = 128 * BK;
  __shared__ __align__(16) u16 smem[2 * TILE];
  u16* As = smem;
  u16* Bs = smem + TILE;

  const size_t kof = (size_t)blockIdx.z * K;
  A += kof; Bt += kof;

  const int tid  = threadIdx.x;
  const int wave = tid >> 6;
  const int lane = tid & 63;
  const int bm   = blockIdx.y * 128;
  const int bn   = blockIdx.x * 128;
  const int wm   = (wave >> 1) * 64;
  const int wn   = (wave & 1) * 64;
  const int quad = lane >> 4;
  const int l16  = lane & 15;

  const int srow = wave * 16 + (lane >> 2);
  const int scol = (lane & 3) * 8;
  const size_t offA = (size_t)(bm + srow) * lda + scol;
  const size_t offB = (size_t)(bn + srow) * ldb + scol;
  const size_t offA64 = (size_t)64 * lda;
  const size_t offB64 = (size_t)64 * ldb;
  const int lds0 = wave * 512;
  const int lds1 = 2048 + wave * 512;

  floatx4 acc[4][4] = {};

  for (int k0 = 0; k0 < K; k0 += BK) {
    __syncthreads();
    load16(A + offA + k0,           As + lds0);
    load16(A + offA + offA64 + k0,  As + lds1);
    load16(Bt + offB + k0,          Bs + lds0);
    load16(Bt + offB + offB64 + k0, Bs + lds1);
    __syncthreads();

    short8 af[4], bf[4];
#pragma unroll
    for (int t = 0; t < 4; ++t) {
      af[t] = *reinterpret_cast<const short8*>(As + (wm + t * 16 + l16) * BK + quad * 8);
      bf[t] = *reinterpret_cast<const short8*>(Bs + (wn + t * 16 + l16) * BK + quad * 8);
    }
#pragma unroll
    for (int mt = 0; mt < 4; ++mt)
#pragma unroll
      for (int nt = 0; nt < 4; ++nt)
        acc[mt][nt] = __builtin_amdgcn_mfma_f32_16x16x32_bf16(
            af[mt], bf[nt], acc[mt][nt], 0, 0, 0);
  }

#pragma unroll
  for (int mt = 0; mt < 4; ++mt)
#pragma unroll
    for (int nt = 0; nt < 4; ++nt) {
      const int row = bm + wm + mt * 16 + quad * 4;
      const int col = bn + wn + nt * 16 + l16;
#pragma unroll
      for (int r = 0; r < 4; ++r) {
        if constexpr (ATOMIC)
          atomicAdd(&C[(size_t)(row + r) * N + col], acc[mt][nt][r]);
        else
          C[(size_t)(row + r) * N + col] = acc[mt][nt][r];
      }
    }
}

// ---------------- single-pass softmax (block per row) ----------------
__global__ __launch_bounds__(256)
void softmax_kernel(const float* __restrict__ S, u16* __restrict__ P) {
  const int row = blockIdx.x, tid = threadIdx.x;
  const int lane = tid & 63, wave = tid >> 6;
  __shared__ float red[4];
  const float4* src = reinterpret_cast<const float4*>(S + (size_t)row * S_SEQ);
  ushort4* dst = reinterpret_cast<ushort4*>(P + (size_t)row * S_SEQ);

  float4 v[4];
  float m = -INFINITY;
#pragma unroll
  for (int t = 0; t < 4; ++t) {
    v[t] = src[tid + t * 256];
    m = fmaxf(m, fmaxf(fmaxf(v[t].x, v[t].y), fmaxf(v[t].z, v[t].w)));
  }
#pragma unroll
  for (int off = 1; off < 64; off <<= 1) m = fmaxf(m, __shfl_xor(m, off));
  if (lane == 0) red[wave] = m;
  __syncthreads();
  m = fmaxf(fmaxf(red[0], red[1]), fmaxf(red[2], red[3]));

  float e[16];
  float l = 0.f;
#pragma unroll
  for (int t = 0; t < 4; ++t) {
    e[4 * t + 0] = __expf(v[t].x - m);
    e[4 * t + 1] = __expf(v[t].y - m);
    e[4 * t + 2] = __expf(v[t].z - m);
    e[4 * t + 3] = __expf(v[t].w - m);
    l += e[4 * t + 0] + e[4 * t + 1] + e[4 * t + 2] + e[4 * t + 3];
  }
#pragma unroll
  for (int off = 1; off < 64; off <<= 1) l += __shfl_xor(l, off);
  __syncthreads();
  if (lane == 0) red[wave] = l;
  __syncthreads();
  const float li = 1.f / (red[0] + red[1] + red[2] + red[3]);

#pragma unroll
  for (int t = 0; t < 4; ++t) {
    ushort4 o;
    o.x = f2b(e[4 * t + 0] * li);
    o.y = f2b(e[4 * t + 1] * li);
    o.z = f2b(e[4 * t + 2] * li);
    o.w = f2b(e[4 * t + 3] * li);
    dst[tid + t * 256] = o;
  }
}

// ---------------- launcher ----------------
// ws (136 MB):
//  [0,8M) Xh  [8,16M) Xl  [16,22M) WtH[3072][1024]  [22,26M) WtL[2048][1024]
//  [0,32M)  P (overlays X/W after projections)
//  [32,36) Qa  [36,40) Qb  [40,44) Ka  [44,48) Kb   (int8 planes)
//  [64,72) Vt[1024][4096] bf16
//  [72,136) Ss fp32 [4096][4096]

extern "C" void kernel_launch(void* const* d_in, const int* in_sizes, int n_in,
                              void* d_out, int out_size, void* d_ws, size_t ws_size,
                              hipStream_t stream) {
  const float* X  = (const float*)d_in[0];
  const float* Wq = (const float*)d_in[1];
  const float* Wk = (const float*)d_in[2];
  const float* Wv = (const float*)d_in[3];
  float* O = (float*)d_out;
  char* ws = (char*)d_ws;

  const size_t MB = 1u << 20;
  u16*   Xh  = (u16*)(ws);
  u16*   Xl  = (u16*)(ws + 8 * MB);
  u16*   WtH = (u16*)(ws + 16 * MB);
  u16*   WtL = (u16*)(ws + 22 * MB);
  u16*   P   = (u16*)(ws);
  char*  Qa  = (char*)(ws + 32 * MB);
  char*  Qb  = (char*)(ws + 36 * MB);
  char*  Ka  = (char*)(ws + 40 * MB);
  char*  Kb  = (char*)(ws + 44 * MB);
  u16*   Vt  = (u16*)(ws + 64 * MB);
  float* Ss  = (float*)(ws + 72 * MB);

  // O accumulated by atomic split-K PV: zero it first
  hipMemsetAsync(O, 0, (size_t)S_SEQ * D_OUT * sizeof(float), stream);

  // phase A: conversions
  split_bf16_kernel<<<(S_SEQ * D_IN / 4 + 255) / 256, 256, 0, stream>>>(
      X, Xh, Xl, S_SEQ * D_IN / 4);
  transpose_w_kernel<<<dim3(32, 32, 3), dim3(32, 8), 0, stream>>>(
      Wq, Wk, Wv, WtH, WtL);

  // phase B: merged QKV projection (768 blocks)
  qkv_kernel<<<dim3(3072 / 128, S_SEQ / 128), 256, 0, stream>>>(
      Xh, Xl, WtH, WtL, Qa, Qb, Ka, Kb, Vt);

  // phase B2: S = fixed-point QK^T / 32, i8 MFMA (2048 blocks)
  s_i8_kernel<<<dim3(S_SEQ / 64, S_SEQ / 128), 256, 0, stream>>>(
      Qa, Qb, Ka, Kb, Ss);

  // phase C: single-pass softmax
  softmax_kernel<<<S_SEQ, 256, 0, stream>>>(Ss, P);

  // phase D: O += P.V, split-K2, atomic accumulate (512 blocks)
  gemm_kernel<true><<<dim3(D_OUT / 128, S_SEQ / 128, 2), 256, 0, stream>>>(
      P, Vt, O, S_SEQ, D_OUT, S_SEQ / 2, S_SEQ, S_SEQ);
}